// Round 9
// baseline (51.438 us; speedup 1.0000x reference)
//
#include <hip/hip_runtime.h>

typedef __attribute__((ext_vector_type(4))) float f32x4;
typedef __attribute__((ext_vector_type(8))) _Float16 f16x8;
typedef __attribute__((ext_vector_type(4))) unsigned short u16x4;

#define NB 8
#define LLEN 512
#define DD 768
#define MW 12
#define HH 384
#define TT (NB * LLEN)      // 4096 tokens
#define SS (LLEN * MW)      // 6144 spans per batch
#define MM (2 * TT)         // 8192 fused GEMM rows (U rows then V rows)

#define PACKH_BLOCKS ((TT * 192) / 256)   // 3072
#define PACKW_BLOCKS ((DD * 192) / 256)   // 576
#define SENT_BLOCKS (DD / 4)              // 192
#define PREP_BLOCKS (PACKH_BLOCKS + PACKW_BLOCKS + SENT_BLOCKS)

// ---------- helpers ----------
__device__ __forceinline__ unsigned short f2h(float x) {
  _Float16 h = (_Float16)x;               // RNE
  return __builtin_bit_cast(unsigned short, h);
}
__device__ __forceinline__ float h2f(unsigned short u) {
  return (float)__builtin_bit_cast(_Float16, u);
}
__device__ __forceinline__ void gload_lds16(const void* g, void* l) {
  __builtin_amdgcn_global_load_lds(
      (const __attribute__((address_space(1))) unsigned int*)g,
      (__attribute__((address_space(3))) unsigned int*)l, 16, 0, 0);
}

// ---------- prep: h -> A [MM][HH] fp16 (fwd rows 0..TT-1, bwd rows TT..),
//                  W -> Bu, Bv [DD][HH] fp16; sentinels -> us,vs fp16 ----------
__global__ __launch_bounds__(256) void prep_k(const float* __restrict__ h,
                                              const float* __restrict__ W,
                                              const float* __restrict__ ss,
                                              const float* __restrict__ es,
                                              unsigned short* __restrict__ A,
                                              unsigned short* __restrict__ Bu,
                                              unsigned short* __restrict__ Bv,
                                              unsigned short* __restrict__ us,
                                              unsigned short* __restrict__ vs) {
  int bid = blockIdx.x;
  if (bid < PACKH_BLOCKS) {
    int idx = bid * 256 + threadIdx.x;        // over TT*192 float4s
    int t = idx / 192;
    int k = (idx - t * 192) * 4;
    f32x4 f = *(const f32x4*)(h + (size_t)idx * 4);
    int row = (k < HH) ? t : TT + t;          // fwd half -> U rows, bwd -> V rows
    int kk = (k < HH) ? k : k - HH;
    u16x4 v;
#pragma unroll
    for (int j = 0; j < 4; ++j) v[j] = f2h(f[j]);
    *(u16x4*)(A + (size_t)row * HH + kk) = v;
  } else if (bid < PACKH_BLOCKS + PACKW_BLOCKS) {
    int idx = (bid - PACKH_BLOCKS) * 256 + threadIdx.x;  // over DD*192 float4s
    int e = idx / 192;
    int k = (idx - e * 192) * 4;
    f32x4 f = *(const f32x4*)(W + (size_t)idx * 4);
    unsigned short* Bm = (k < HH) ? Bu : Bv;
    int kk = (k < HH) ? k : k - HH;
    u16x4 v;
#pragma unroll
    for (int j = 0; j < 4; ++j) v[j] = f2h(f[j]);
    *(u16x4*)(Bm + (size_t)e * HH + kk) = v;
  } else {
    // sentinel projections: 4 e-values per block, 64 lanes each (f32 math)
    int e = (bid - PACKH_BLOCKS - PACKW_BLOCKS) * 4 + (threadIdx.x >> 6);
    int lane = threadIdx.x & 63;
    float a = 0.f, b = 0.f;
    const float* w = W + (size_t)e * DD;
    for (int j = lane; j < HH; j += 64) {
      a += ss[j] * w[j];
      b += es[j] * w[HH + j];
    }
#pragma unroll
    for (int off = 32; off > 0; off >>= 1) {
      a += __shfl_down(a, off);
      b += __shfl_down(b, off);
    }
    if (lane == 0) { us[e] = f2h(a); vs[e] = f2h(b); }
  }
}

// ---------- fp16 GEMM: C[8192][768] = A[M][HH] * B^T[N][HH], C fp16 ----------
// BM=128, BN=96, 6 kc-iters, DOUBLE-BUFFERED: issue next-tile global_load_lds
// before current tile's ds_read+MFMA; ONE barrier per iter (its vmcnt drain
// lands after MFMA covered the load latency). 56 KB LDS -> 2 blocks/CU.
// Grid 512 = 2/CU; bid&63 keeps an M-panel's 8 N-blocks on one XCD.
__global__ __launch_bounds__(256) void gemm_k(const unsigned short* __restrict__ A,
                                              const unsigned short* __restrict__ Bu,
                                              const unsigned short* __restrict__ Bv,
                                              unsigned short* __restrict__ C) {
  __shared__ unsigned short As[2][128 * 64];   // 32 KB
  __shared__ unsigned short Bs[2][96 * 64];    // 24 KB

  const int bid = blockIdx.x;
  const int bx = bid & 63, by = bid >> 6;
  const int tid = threadIdx.x;
  const int lane = tid & 63;
  const int w = tid >> 6;
  const int wr = w >> 1, wc = w & 1;           // 2x2 waves -> each 64x48
  const int l16 = lane & 15, l4 = lane >> 4;
  const int row0 = bx * 128;
  const int col0 = by * 96;
  const char* Bb = (const char*)((row0 < TT) ? Bu : Bv);
  const char* Ab = (const char*)A;

  f32x4 acc[4][3] = {};

#define STAGE(buf, kc)                                                          \
  {                                                                             \
    _Pragma("unroll")                                                           \
    for (int r = 0; r < 4; ++r) {                                               \
      int o = (r * 256 + tid) * 16;                                             \
      int row = o >> 7, colb = o & 127;                                         \
      gload_lds16(Ab + ((size_t)(row0 + row) * HH + (kc)) * 2 + colb,           \
                  (char*)As[buf] + o);                                          \
    }                                                                           \
    _Pragma("unroll")                                                           \
    for (int r = 0; r < 3; ++r) {                                               \
      int o = (r * 256 + tid) * 16;                                             \
      int row = o >> 7, colb = o & 127;                                         \
      gload_lds16(Bb + ((size_t)(col0 + row) * HH + (kc)) * 2 + colb,           \
                  (char*)Bs[buf] + o);                                          \
    }                                                                           \
  }

  STAGE(0, 0);
  __syncthreads();                             // drains vmcnt(0): tile 0 ready

#pragma unroll
  for (int i = 0; i < 6; ++i) {
    const int cur = i & 1;
    if (i < 5) STAGE(cur ^ 1, (i + 1) * 64);   // prefetch next tile (other buf)

    const unsigned short* Ac = As[cur];
    const unsigned short* Bc = Bs[cur];
    f16x8 af[2][4], bf[2][3];
#pragma unroll
    for (int ks = 0; ks < 2; ++ks)
#pragma unroll
      for (int m = 0; m < 4; ++m)
        af[ks][m] = *(const f16x8*)&Ac[(wr * 64 + m * 16 + l16) * 64 + ks * 32 + l4 * 8];
#pragma unroll
    for (int ks = 0; ks < 2; ++ks)
#pragma unroll
      for (int n = 0; n < 3; ++n)
        bf[ks][n] = *(const f16x8*)&Bc[(wc * 48 + n * 16 + l16) * 64 + ks * 32 + l4 * 8];

#pragma unroll
    for (int m = 0; m < 4; ++m)
#pragma unroll
      for (int n = 0; n < 3; ++n) {
        acc[m][n] = __builtin_amdgcn_mfma_f32_16x16x32_f16(af[0][m], bf[0][n], acc[m][n], 0, 0, 0);
        acc[m][n] = __builtin_amdgcn_mfma_f32_16x16x32_f16(af[1][m], bf[1][n], acc[m][n], 0, 0, 0);
      }
    __syncthreads();                           // next tile landed; cur buf free
  }
#undef STAGE

  // epilogue: D row=(lane>>4)*4+reg, col=lane&15 (m89-verified; dtype-independent); store fp16
#pragma unroll
  for (int m = 0; m < 4; ++m) {
    int grow = row0 + wr * 64 + m * 16 + l4 * 4;
#pragma unroll
    for (int n = 0; n < 3; ++n) {
      int gcol = col0 + wc * 48 + n * 16 + l16;
#pragma unroll
      for (int r = 0; r < 4; ++r)
        C[(size_t)(grow + r) * DD + gcol] = f2h(acc[m][n][r]);
    }
  }
}

// ---------- assembly: one block per token (XCD-swizzled), loops its 12 spans ----------
__global__ __launch_bounds__(192) void assemble_k(const int* __restrict__ span,
                                                  const unsigned short* __restrict__ U,
                                                  const unsigned short* __restrict__ V,
                                                  const unsigned short* __restrict__ us,
                                                  const unsigned short* __restrict__ vs,
                                                  const float* __restrict__ bias,
                                                  float* __restrict__ out) {
  const int bid = blockIdx.x;
  const int tk = (bid & 7) * (TT / 8) + (bid >> 3);   // XCD-chunked token order
  const int b = tk >> 9;                     // /512
  const int l = tk & 511;
  const int t0 = b * LLEN;
  const int e4 = threadIdx.x;                // 0..191, covers 4 e's
  const u16x4* U4 = (const u16x4*)U;
  const u16x4* V4 = (const u16x4*)V;
  const f32x4 bb = ((const f32x4*)bias)[e4];
  const int2* sp = (const int2*)(span + ((size_t)b * SS + (size_t)l * MW) * 2);
  f32x4* out4 = (f32x4*)out + ((size_t)b * SS + (size_t)l * MW) * 192 + e4;

#pragma unroll 4
  for (int wdx = 0; wdx < MW; ++wdx) {
    const int2 se = sp[wdx];
    const int start = se.x, end = se.y;
    u16x4 pe = U4[(size_t)(t0 + end) * 192 + e4];
    u16x4 pv = (end + 1 >= LLEN) ? ((const u16x4*)vs)[e4]
                                 : V4[(size_t)(t0 + end + 1) * 192 + e4];
    u16x4 mu = (start == 0) ? ((const u16x4*)us)[e4]
                            : U4[(size_t)(t0 + start - 1) * 192 + e4];
    u16x4 mv = V4[(size_t)(t0 + start) * 192 + e4];
    f32x4 r;
#pragma unroll
    for (int j = 0; j < 4; ++j) {
      float x = h2f(pe[j]) + h2f(pv[j]) - h2f(mu[j]) - h2f(mv[j]) + bb[j];
      r[j] = fmaxf(x, 0.f);
    }
    out4[(size_t)wdx * 192] = r;
  }
}

// ---------- naive fallback (only if ws too small) ----------
__global__ __launch_bounds__(256) void naive_k(const float* __restrict__ h,
                                               const int* __restrict__ span,
                                               const float* __restrict__ W,
                                               const float* __restrict__ bias,
                                               const float* __restrict__ ss,
                                               const float* __restrict__ es,
                                               float* __restrict__ out) {
  int bs = blockIdx.x;
  int b = bs / SS;
  int start = span[(size_t)bs * 2 + 0];
  int end   = span[(size_t)bs * 2 + 1];
  __shared__ float rep[DD];
  const float* hb = h + (size_t)b * LLEN * DD;
  for (int k = threadIdx.x; k < HH; k += blockDim.x) {
    float fs = (start == 0) ? ss[k] : hb[(size_t)(start - 1) * DD + k];
    rep[k] = hb[(size_t)end * DD + k] - fs;
    float bstart = (end + 1 >= LLEN) ? es[k] : hb[(size_t)(end + 1) * DD + HH + k];
    rep[HH + k] = bstart - hb[(size_t)start * DD + HH + k];
  }
  __syncthreads();
  for (int e = threadIdx.x; e < DD; e += blockDim.x) {
    const float* w = W + (size_t)e * DD;
    float acc = bias[e];
    for (int k = 0; k < DD; k += 4) {
      acc += rep[k] * w[k] + rep[k + 1] * w[k + 1] + rep[k + 2] * w[k + 2] + rep[k + 3] * w[k + 3];
    }
    out[(size_t)bs * DD + e] = fmaxf(acc, 0.f);
  }
}

extern "C" void kernel_launch(void* const* d_in, const int* in_sizes, int n_in,
                              void* d_out, int out_size, void* d_ws, size_t ws_size,
                              hipStream_t stream) {
  const float* h  = (const float*)d_in[0];
  const int* span = (const int*)d_in[1];
  const float* W  = (const float*)d_in[2];
  const float* bias = (const float*)d_in[3];
  const float* ss = (const float*)d_in[4];
  const float* es = (const float*)d_in[5];
  float* out = (float*)d_out;

  const size_t szUV = (size_t)MM * DD * sizeof(unsigned short);   // 12.58 MB (U+V fp16)
  const size_t szA  = (size_t)MM * HH * sizeof(unsigned short);   // 6.29 MB
  const size_t szB  = (size_t)DD * HH * sizeof(unsigned short);   // 0.59 MB (each of u,v)
  const size_t szS  = DD * sizeof(unsigned short);
  const size_t need = szUV + szA + 2 * szB + 2 * szS;             // ~20.1 MB

  if (ws_size < need) {
    naive_k<<<NB * SS, 256, 0, stream>>>(h, span, W, bias, ss, es, out);
    return;
  }

  char* ws = (char*)d_ws;
  unsigned short* U  = (unsigned short*)ws;                // [TT][DD] fp16
  unsigned short* V  = U + (size_t)TT * DD;                // [TT][DD] fp16
  unsigned short* A  = (unsigned short*)(ws + szUV);       // [MM][HH] fp16
  unsigned short* Bu = A + (size_t)MM * HH;
  unsigned short* Bv = Bu + (size_t)DD * HH;
  unsigned short* us = Bv + (size_t)DD * HH;
  unsigned short* vs = us + DD;

  prep_k<<<PREP_BLOCKS, 256, 0, stream>>>(h, W, ss, es, A, Bu, Bv, us, vs);
  gemm_k<<<512, 256, 0, stream>>>(A, Bu, Bv, U);
  assemble_k<<<TT, 192, 0, stream>>>(span, U, V, us, vs, bias, out);
}

// Round 10
// 49.730 us; speedup vs baseline: 1.0343x; 1.0343x over previous
//
#include <hip/hip_runtime.h>

typedef __attribute__((ext_vector_type(4))) float f32x4;
typedef __attribute__((ext_vector_type(8))) _Float16 f16x8;
typedef __attribute__((ext_vector_type(4))) unsigned short u16x4;

#define NB 8
#define LLEN 512
#define DD 768
#define MW 12
#define HH 384
#define TT (NB * LLEN)      // 4096 tokens
#define SS (LLEN * MW)      // 6144 spans per batch
#define MM (2 * TT)         // 8192 packed A rows (fwd rows then bwd rows)

#define BT 32               // tokens per fused block
#define BE 192              // e-slice per fused block
#define WROWS 48            // U/V window rows (BT + 12 halo, rounded to 48)
#define PADW 204            // UV LDS row pitch in fp16 (bank-disjoint for 4 lane-groups)

#define PACKH_BLOCKS ((TT * 192) / 256)   // 3072
#define PACKW_BLOCKS ((DD * 192) / 256)   // 576
#define SENT_BLOCKS (DD / 4)              // 192
#define PREP_BLOCKS (PACKH_BLOCKS + PACKW_BLOCKS + SENT_BLOCKS)

// ---------- helpers ----------
__device__ __forceinline__ unsigned short f2h(float x) {
  _Float16 h = (_Float16)x;               // RNE
  return __builtin_bit_cast(unsigned short, h);
}
__device__ __forceinline__ float h2f(unsigned short u) {
  return (float)__builtin_bit_cast(_Float16, u);
}
__device__ __forceinline__ void gload_lds16(const void* g, void* l) {
  __builtin_amdgcn_global_load_lds(
      (const __attribute__((address_space(1))) unsigned int*)g,
      (__attribute__((address_space(3))) unsigned int*)l, 16, 0, 0);
}

// ---------- prep: h -> A [MM][HH] fp16 (fwd rows 0..TT-1, bwd rows TT..),
//                  W -> Bu, Bv [DD][HH] fp16; sentinels -> us,vs fp16 ----------
__global__ __launch_bounds__(256) void prep_k(const float* __restrict__ h,
                                              const float* __restrict__ W,
                                              const float* __restrict__ ss,
                                              const float* __restrict__ es,
                                              unsigned short* __restrict__ A,
                                              unsigned short* __restrict__ Bu,
                                              unsigned short* __restrict__ Bv,
                                              unsigned short* __restrict__ us,
                                              unsigned short* __restrict__ vs) {
  int bid = blockIdx.x;
  if (bid < PACKH_BLOCKS) {
    int idx = bid * 256 + threadIdx.x;        // over TT*192 float4s
    int t = idx / 192;
    int k = (idx - t * 192) * 4;
    f32x4 f = *(const f32x4*)(h + (size_t)idx * 4);
    int row = (k < HH) ? t : TT + t;          // fwd half -> U rows, bwd -> V rows
    int kk = (k < HH) ? k : k - HH;
    u16x4 v;
#pragma unroll
    for (int j = 0; j < 4; ++j) v[j] = f2h(f[j]);
    *(u16x4*)(A + (size_t)row * HH + kk) = v;
  } else if (bid < PACKH_BLOCKS + PACKW_BLOCKS) {
    int idx = (bid - PACKH_BLOCKS) * 256 + threadIdx.x;  // over DD*192 float4s
    int e = idx / 192;
    int k = (idx - e * 192) * 4;
    f32x4 f = *(const f32x4*)(W + (size_t)idx * 4);
    unsigned short* Bm = (k < HH) ? Bu : Bv;
    int kk = (k < HH) ? k : k - HH;
    u16x4 v;
#pragma unroll
    for (int j = 0; j < 4; ++j) v[j] = f2h(f[j]);
    *(u16x4*)(Bm + (size_t)e * HH + kk) = v;
  } else {
    // sentinel projections: 4 e-values per block, 64 lanes each (f32 math)
    int e = (bid - PACKH_BLOCKS - PACKW_BLOCKS) * 4 + (threadIdx.x >> 6);
    int lane = threadIdx.x & 63;
    float a = 0.f, b = 0.f;
    const float* w = W + (size_t)e * DD;
    for (int j = lane; j < HH; j += 64) {
      a += ss[j] * w[j];
      b += es[j] * w[HH + j];
    }
#pragma unroll
    for (int off = 32; off > 0; off >>= 1) {
      a += __shfl_down(a, off);
      b += __shfl_down(b, off);
    }
    if (lane == 0) { us[e] = f2h(a); vs[e] = f2h(b); }
  }
}

// ---------- fused GEMM+assemble ----------
// Per block: batch b, token window [T0-1, T0+46] (48 rows, clamped), e-slice [E0,E0+192).
// Phase 1: U/V tile GEMM (M=96: 48 U-rows + 48 V-rows, N=192, K=384) with
//          global_load_lds staging; waves 2x2: wr selects U/V, wc selects N-half.
// Phase 2: acc -> fp16 UV tile in LDS (union over dead staging buffers).
// Phase 3: assemble 32 tokens x 12 widths x 192 e straight from LDS -> out.
// Grid 512 = 8b x 16tok x 4e, 2 blocks/CU; e-siblings (sharing A rows) on one XCD.
__global__ __launch_bounds__(256) void fused_k(const unsigned short* __restrict__ A,
                                               const unsigned short* __restrict__ Bu,
                                               const unsigned short* __restrict__ Bv,
                                               const int* __restrict__ span,
                                               const unsigned short* __restrict__ us,
                                               const unsigned short* __restrict__ vs,
                                               const float* __restrict__ bias,
                                               float* __restrict__ out) {
  __shared__ char lds[96 * 64 * 2 + 2 * 192 * 64 * 2];  // 61440 B union
  __shared__ int2 spans[BT * MW];                        // 3 KB

  const int bid = blockIdx.x;
  // bid = (g>>3)*32 + ec*8 + (g&7): the 4 e-siblings of token-group g share bid%8 (XCD)
  const int g = ((bid >> 5) << 3) | (bid & 7);
  const int ec = (bid >> 3) & 3;
  const int b = g >> 4;
  const int tch = g & 15;
  const int T0 = tch * BT;
  const int E0 = ec * BE;

  const int tid = threadIdx.x;
  const int lane = tid & 63;
  const int w = tid >> 6;
  const int wr = w >> 1, wc = w & 1;
  const int l16 = lane & 15, l4 = lane >> 4;

  // stage this block's 384 spans (int32 pairs, contiguous)
  {
    const int2* sp = (const int2*)span + (size_t)b * SS + (size_t)T0 * MW;
    for (int s = tid; s < BT * MW; s += 256) spans[s] = sp[s];
  }

  unsigned short* As = (unsigned short*)lds;   // [96][64]  rows 0-47: U(fwd), 48-95: V(bwd)
  unsigned short* Bf = As + 96 * 64;           // [192][64] W fwd cols slice
  unsigned short* Bb = Bf + 192 * 64;          // [192][64] W bwd cols slice

  f32x4 acc[3][6] = {};

  for (int kc = 0; kc < HH; kc += 64) {
#pragma unroll
    for (int r = 0; r < 3; ++r) {
      int o = (r * 256 + tid) * 16;            // byte offset; 128 B per LDS row
      int rr = o >> 7, colb = o & 127;
      int tloc = T0 - 1 + (rr < WROWS ? rr : rr - WROWS);
      tloc = min(max(tloc, 0), LLEN - 1);      // halo clamp (clamped rows unused)
      size_t arow = (size_t)(rr < WROWS ? 0 : TT) + (size_t)b * LLEN + tloc;
      gload_lds16((const char*)A + (arow * HH + kc) * 2 + colb, (char*)As + o);
    }
#pragma unroll
    for (int r = 0; r < 6; ++r) {
      int o = (r * 256 + tid) * 16;
      int rr = o >> 7, colb = o & 127;
      gload_lds16((const char*)Bu + ((size_t)(E0 + rr) * HH + kc) * 2 + colb, (char*)Bf + o);
      gload_lds16((const char*)Bv + ((size_t)(E0 + rr) * HH + kc) * 2 + colb, (char*)Bb + o);
    }
    __syncthreads();

    const unsigned short* Am = As + (wr * WROWS) * 64;
    const unsigned short* Bm = (wr == 0) ? Bf : Bb;
    f16x8 af[2][3], bf[2][6];
#pragma unroll
    for (int ks = 0; ks < 2; ++ks)
#pragma unroll
      for (int m = 0; m < 3; ++m)
        af[ks][m] = *(const f16x8*)&Am[(m * 16 + l16) * 64 + ks * 32 + l4 * 8];
#pragma unroll
    for (int ks = 0; ks < 2; ++ks)
#pragma unroll
      for (int n = 0; n < 6; ++n)
        bf[ks][n] = *(const f16x8*)&Bm[(wc * 96 + n * 16 + l16) * 64 + ks * 32 + l4 * 8];

#pragma unroll
    for (int m = 0; m < 3; ++m)
#pragma unroll
      for (int n = 0; n < 6; ++n) {
        acc[m][n] = __builtin_amdgcn_mfma_f32_16x16x32_f16(af[0][m], bf[0][n], acc[m][n], 0, 0, 0);
        acc[m][n] = __builtin_amdgcn_mfma_f32_16x16x32_f16(af[1][m], bf[1][n], acc[m][n], 0, 0, 0);
      }
    __syncthreads();                           // also frees staging for the union below
  }

  // Phase 2: acc -> fp16 UV tile (reuses staging LDS; all waves are past last barrier)
  unsigned short* Uld = (unsigned short*)lds;  // [48][PADW]  Uld[i] = U[T0-1+i]
  unsigned short* Vld = Uld + WROWS * PADW;    // [48][PADW]  Vld[i] = V[T0-1+i]
  {
    unsigned short* Cm = (wr == 0) ? Uld : Vld;
#pragma unroll
    for (int m = 0; m < 3; ++m) {
      int row = m * 16 + l4 * 4;
#pragma unroll
      for (int n = 0; n < 6; ++n) {
        int col = wc * 96 + n * 16 + l16;
#pragma unroll
        for (int r = 0; r < 4; ++r)
          Cm[(row + r) * PADW + col] = f2h(acc[m][n][r]);
      }
    }
  }
  __syncthreads();

  // Phase 3: assemble out[b, (T0+l)*12+w, E0:E0+192] from LDS
  const u16x4* U4 = (const u16x4*)Uld;         // row pitch PADW/4 = 51
  const u16x4* V4 = (const u16x4*)Vld;
  const u16x4* us4 = (const u16x4*)us + (E0 >> 2);
  const u16x4* vs4 = (const u16x4*)vs + (E0 >> 2);
  const f32x4* bias4 = (const f32x4*)bias + (E0 >> 2);
  f32x4* out4 = (f32x4*)out + ((size_t)b * SS + (size_t)T0 * MW) * (DD / 4) + (E0 >> 2);

  int e4 = tid % 48;
  int lw = tid / 48;
#pragma unroll 4
  for (int it = 0; it < (BT * MW * 48) / 256; ++it) {   // 72 iters
    const int2 se = spans[lw];
    const int start = se.x, end = se.y;
    u16x4 pe = U4[(end - T0 + 1) * 51 + e4];
    u16x4 pv = (end + 1 >= LLEN) ? vs4[e4] : V4[(end - T0 + 2) * 51 + e4];
    u16x4 mu = (start == 0) ? us4[e4] : U4[(start - T0) * 51 + e4];
    u16x4 mv = V4[(start - T0 + 1) * 51 + e4];
    f32x4 bb = bias4[e4];
    f32x4 r;
#pragma unroll
    for (int j = 0; j < 4; ++j) {
      float x = h2f(pe[j]) + h2f(pv[j]) - h2f(mu[j]) - h2f(mv[j]) + bb[j];
      r[j] = fmaxf(x, 0.f);
    }
    out4[(size_t)lw * (DD / 4) + e4] = r;
    // idx += 256  ==  e4 += 16 (mod 48), lw += 5 (+carry)
    e4 += 16; lw += 5;
    if (e4 >= 48) { e4 -= 48; lw += 1; }
  }
}

// ---------- naive fallback (only if ws too small) ----------
__global__ __launch_bounds__(256) void naive_k(const float* __restrict__ h,
                                               const int* __restrict__ span,
                                               const float* __restrict__ W,
                                               const float* __restrict__ bias,
                                               const float* __restrict__ ss,
                                               const float* __restrict__ es,
                                               float* __restrict__ out) {
  int bs = blockIdx.x;
  int b = bs / SS;
  int start = span[(size_t)bs * 2 + 0];
  int end   = span[(size_t)bs * 2 + 1];
  __shared__ float rep[DD];
  const float* hb = h + (size_t)b * LLEN * DD;
  for (int k = threadIdx.x; k < HH; k += blockDim.x) {
    float fs = (start == 0) ? ss[k] : hb[(size_t)(start - 1) * DD + k];
    rep[k] = hb[(size_t)end * DD + k] - fs;
    float bstart = (end + 1 >= LLEN) ? es[k] : hb[(size_t)(end + 1) * DD + HH + k];
    rep[HH + k] = bstart - hb[(size_t)start * DD + HH + k];
  }
  __syncthreads();
  for (int e = threadIdx.x; e < DD; e += blockDim.x) {
    const float* w = W + (size_t)e * DD;
    float acc = bias[e];
    for (int k = 0; k < DD; k += 4) {
      acc += rep[k] * w[k] + rep[k + 1] * w[k + 1] + rep[k + 2] * w[k + 2] + rep[k + 3] * w[k + 3];
    }
    out[(size_t)bs * DD + e] = fmaxf(acc, 0.f);
  }
}

extern "C" void kernel_launch(void* const* d_in, const int* in_sizes, int n_in,
                              void* d_out, int out_size, void* d_ws, size_t ws_size,
                              hipStream_t stream) {
  const float* h  = (const float*)d_in[0];
  const int* span = (const int*)d_in[1];
  const float* W  = (const float*)d_in[2];
  const float* bias = (const float*)d_in[3];
  const float* ss = (const float*)d_in[4];
  const float* es = (const float*)d_in[5];
  float* out = (float*)d_out;

  const size_t szA  = (size_t)MM * HH * sizeof(unsigned short);   // 6.29 MB
  const size_t szB  = (size_t)DD * HH * sizeof(unsigned short);   // 0.59 MB (each)
  const size_t szS  = DD * sizeof(unsigned short);
  const size_t need = szA + 2 * szB + 2 * szS;                    // ~7.5 MB

  if (ws_size < need) {
    naive_k<<<NB * SS, 256, 0, stream>>>(h, span, W, bias, ss, es, out);
    return;
  }

  char* ws = (char*)d_ws;
  unsigned short* A  = (unsigned short*)ws;                // [MM][HH] fp16
  unsigned short* Bu = A + (size_t)MM * HH;
  unsigned short* Bv = Bu + (size_t)DD * HH;
  unsigned short* us = Bv + (size_t)DD * HH;
  unsigned short* vs = us + DD;

  prep_k<<<PREP_BLOCKS, 256, 0, stream>>>(h, W, ss, es, A, Bu, Bv, us, vs);
  fused_k<<<512, 256, 0, stream>>>(A, Bu, Bv, span, us, vs, bias, out);
}